// Round 9
// baseline (697.966 us; speedup 1.0000x reference)
//
#include <hip/hip_runtime.h>
#include <math.h>

#define N_PATHS 50000
#define N_LINKS 10000
#define LPATH   8
#define DEG     40
#define DIM     64
#define G3      192
#define ITERS   8

typedef float f32x4  __attribute__((ext_vector_type(4)));
typedef short bf16x8 __attribute__((ext_vector_type(8)));

__device__ __forceinline__ float fsigmoid(float x){ return 1.0f/(1.0f + __expf(-x)); }
__device__ __forceinline__ float ftanh(float x){ return 1.0f - 2.0f/(__expf(2.0f*x) + 1.0f); }
__device__ __forceinline__ unsigned short bf16_rne(float v){
  unsigned u = __float_as_uint(v);
  return (unsigned short)((u + 0x7FFFu + ((u>>16)&1u)) >> 16);
}
// packed bf16 pair: lo16 = bf16(a), hi16 = bf16(b). RNE, single HW op on gfx950.
__device__ __forceinline__ unsigned pack_bf16(float a, float b){
  unsigned r;
  asm("v_cvt_pk_bf16_f32 %0, %1, %2" : "=v"(r) : "v"(a), "v"(b));
  return r;
}
__device__ __forceinline__ float lo16f(unsigned v){ return __uint_as_float(v << 16); }
__device__ __forceinline__ float hi16f(unsigned v){ return __uint_as_float(v & 0xFFFF0000u); }
// split 8 fp32 into bf16 hi + bf16 residual
__device__ __forceinline__ void split8(const float* s, bf16x8& hi, bf16x8& lo){
  #pragma unroll
  for (int e=0;e<8;e++){
    unsigned short hb = bf16_rne(s[e]);
    float lof = s[e] - __uint_as_float(((unsigned)hb)<<16);
    hi[e] = (short)hb; lo[e] = (short)bf16_rne(lof);
  }
}
__device__ __forceinline__ void accum8(float* a, uint4 v){
  unsigned x[4] = {v.x, v.y, v.z, v.w};
  #pragma unroll
  for (int q=0;q<4;q++){
    a[2*q]   += __uint_as_float((x[q]&0xFFFFu)<<16);
    a[2*q+1] += __uint_as_float(x[q]&0xFFFF0000u);
  }
}

// ---------------- path embedding ----------------
__global__ __launch_bounds__(256) void path_embed(
    const float* __restrict__ ft, const float* __restrict__ fp, const float* __restrict__ fps,
    const float* __restrict__ w1, const float* __restrict__ b1,
    const float* __restrict__ w2, const float* __restrict__ b2,
    float* __restrict__ path_state)
{
  __shared__ float h1[4][DIM];
  int j  = threadIdx.x & 63;
  int pl = threadIdx.x >> 6;
  int p  = blockIdx.x*4 + pl;
  float x0 = ft[p]*1e-4f, x1 = fp[p]*1e-3f, x2 = fps[p]*1e-3f;
  float h = b1[j] + x0*w1[0*DIM+j] + x1*w1[1*DIM+j] + x2*w1[2*DIM+j];
  h1[pl][j] = fmaxf(h, 0.f);
  __syncthreads();
  float acc = b2[j];
  #pragma unroll 8
  for (int k=0;k<DIM;k++) acc = fmaf(h1[pl][k], w2[k*DIM+j], acc);
  path_state[p*DIM+j] = fmaxf(acc, 0.f);
}

// ---------------- link embedding ----------------
__global__ __launch_bounds__(256) void link_embed(
    const float* __restrict__ ft, const float* __restrict__ cap, const int* __restrict__ ptl,
    const float* __restrict__ w1, const float* __restrict__ b1,
    const float* __restrict__ w2, const float* __restrict__ b2,
    float* __restrict__ link_state)
{
  __shared__ float h1[4][DIM];
  int j  = threadIdx.x & 63;
  int wl = threadIdx.x >> 6;
  int l  = blockIdx.x*4 + wl;
  float s = 0.f;
  if (j < DEG) s = ft[ptl[(l*DEG + j)*2 + 0]];
  #pragma unroll
  for (int off=32; off; off>>=1) s += __shfl_down(s, off);
  float load = __shfl(s, 0) / (cap[l]*1e9f);
  float x0 = cap[l]*1e-5f;
  float h = b1[j] + x0*w1[0*DIM+j] + load*w1[1*DIM+j];
  h1[wl][j] = fmaxf(h, 0.f);
  __syncthreads();
  float acc = b2[j];
  #pragma unroll 8
  for (int k=0;k<DIM;k++) acc = fmaf(h1[wl][k], w2[k*DIM+j], acc);
  link_state[l*DIM+j] = fmaxf(acc, 0.f);
}

// ---------------- pack 4 weight mats into bf16 MFMA fragments ----------------
// m: 0=pg_wh, 1=pg_wx, 2=lg_wx, 3=lg_wh. frag f=nt*2+kc.
// elem i of lane l = w[kc*32+(l>>4)*8+i][nt*16+(l&15)]  (A- and B-operand maps coincide)
__global__ __launch_bounds__(256) void pack_frags(
    const float* __restrict__ pg_wh, const float* __restrict__ pg_wx,
    const float* __restrict__ lg_wx, const float* __restrict__ lg_wh,
    unsigned short* __restrict__ whf)
{
  int tid = blockIdx.x*256 + threadIdx.x;
  if (tid >= 4*24*512) return;
  int i = tid & 7, l = (tid>>3)&63, f = (tid>>9)%24, m = tid/(24*512);
  int nt = f>>1, kc = f&1;
  int k = kc*32 + (l>>4)*8 + i;
  int n = nt*16 + (l&15);
  const float* src = (m==0)?pg_wh : (m==1)?pg_wx : (m==2)?lg_wx : lg_wh;
  whf[tid] = bf16_rne(src[k*G3 + n]);
}

// ---------------- initial LX, dim-grouped packed bf16 ----------------
// LXq[link][dim][{z,r,q,pad}] (4 ushorts per dim, 512 B per link row)
__global__ __launch_bounds__(192) void compute_lx(
    const float* __restrict__ link_state, const float* __restrict__ wx,
    const float* __restrict__ bx, const float* __restrict__ bh,
    unsigned short* __restrict__ LXq)
{
  __shared__ float ls[4][DIM];
  int g  = threadIdx.x;
  int l0 = blockIdx.x*4;
  if (g < DIM){
    #pragma unroll
    for (int li=0; li<4; li++) ls[li][g] = link_state[(l0+li)*DIM+g];
  }
  __syncthreads();
  float b = bx[g] + (g < 128 ? bh[g] : 0.f);
  float a0=b, a1=b, a2=b, a3=b;
  #pragma unroll 8
  for (int k=0;k<DIM;k++){
    float w = wx[k*G3+g];
    a0 = fmaf(ls[0][k], w, a0);
    a1 = fmaf(ls[1][k], w, a1);
    a2 = fmaf(ls[2][k], w, a2);
    a3 = fmaf(ls[3][k], w, a3);
  }
  int comp = g >> 6, dim = g & 63;
  int pos = dim*4 + comp;
  LXq[(size_t)(l0+0)*256+pos]=bf16_rne(a0);
  LXq[(size_t)(l0+1)*256+pos]=bf16_rne(a1);
  LXq[(size_t)(l0+2)*256+pos]=bf16_rne(a2);
  LXq[(size_t)(l0+3)*256+pos]=bf16_rne(a3);
}

// ---------------- MFMA 8-step GRU scan: transposed-D, 2 tiles/block, LX prefetch ----------------
// block = 4 waves, TWO independent 16-path tiles. Wave w owns dims w*16..+15 of both tiles.
// mfma(W_frag, h_frag, acc): lane holds path lr, dims w*16+lg*4+reg. 1 barrier/step.
__global__ __launch_bounds__(256) void path_scan_mfma(
    const unsigned short* __restrict__ LXq, const int* __restrict__ ltp,
    const unsigned short* __restrict__ whf, const float* __restrict__ bh,
    float* __restrict__ path_state, unsigned short* __restrict__ seq16)
{
  __shared__ __align__(16) unsigned short htile[2][2][16*72];  // [tile][buf][path][dim]
  __shared__ int ltps[256];
  int tid = threadIdx.x, l = tid & 63, w = tid >> 6;
  int lg = l >> 4, lr = l & 15;
  int p0 = blockIdx.x*32;
  if (p0 > N_PATHS-32) p0 = N_PATHS-32;   // overlap tile recomputed identically (benign race)

  // this wave's 6 W-fragments of pg_wh (nt = w, w+4, w+8 -> z, r, q)
  bf16x8 bf[3][2];
  #pragma unroll
  for (int j=0;j<3;j++){
    int nt = w + j*4;
    bf[j][0] = *(const bf16x8*)(whf + (size_t)(nt*2+0)*512 + l*8);
    bf[j][1] = *(const bf16x8*)(whf + (size_t)(nt*2+1)*512 + l*8);
  }
  float bhq[4];
  #pragma unroll
  for (int r=0;r<4;r++) bhq[r] = bh[128 + w*16 + lg*4 + r];

  ltps[tid] = ltp[(size_t)p0*LPATH + tid];   // 32 paths x 8 = 256

  // stage h -> htile[*][0] (coalesced float4 reads, packed 8B LDS writes)
  #pragma unroll
  for (int rep=0; rep<2; rep++){
    int idx = rep*256 + tid;           // 0..511
    int pi = idx >> 4, c4 = (idx & 15)*4;
    float4 v = *(const float4*)(path_state + (size_t)(p0+pi)*DIM + c4);
    uint2 u = make_uint2(pack_bf16(v.x, v.y), pack_bf16(v.z, v.w));
    *(uint2*)&htile[pi>>4][0][(pi&15)*72 + c4] = u;
  }
  // fp32 h_old per tile: path p0+ti*16+lr, dims w*16+lg*4.. (contiguous float4)
  f32x4 hold0 = *(const f32x4*)(path_state + (size_t)(p0+lr   )*DIM + w*16 + lg*4);
  f32x4 hold1 = *(const f32x4*)(path_state + (size_t)(p0+16+lr)*DIM + w*16 + lg*4);

  __syncthreads();

  unsigned short* seqp0 = seq16 + ((size_t)(p0+lr   )*LPATH)*DIM + w*16 + lg*4;
  unsigned short* seqp1 = seq16 + ((size_t)(p0+16+lr)*LPATH)*DIM + w*16 + lg*4;
  const size_t dimoff = (size_t)(w*16 + lg*4)*4;
  int cur = 0;

  // prefetch t=0 LX for both tiles
  uint4 c0a, c0b, c1a, c1b;
  {
    const unsigned short* x0 = LXq + (size_t)ltps[lr*LPATH]*256 + dimoff;
    const unsigned short* x1 = LXq + (size_t)ltps[(16+lr)*LPATH]*256 + dimoff;
    c0a = *(const uint4*)x0; c0b = *(const uint4*)(x0+8);
    c1a = *(const uint4*)x1; c1b = *(const uint4*)(x1+8);
  }

  for (int t=0; t<LPATH; t++){
    // 1) issue NEXT step's LX gather (full step to land)
    int tn = (t < LPATH-1) ? t+1 : t;
    const unsigned short* n0 = LXq + (size_t)ltps[lr*LPATH + tn]*256 + dimoff;
    const unsigned short* n1 = LXq + (size_t)ltps[(16+lr)*LPATH + tn]*256 + dimoff;
    uint4 n0a = *(const uint4*)n0, n0b = *(const uint4*)(n0+8);
    uint4 n1a = *(const uint4*)n1, n1b = *(const uint4*)(n1+8);

    // 2) h fragments + 12 MFMAs (both tiles, independent chains)
    bf16x8 h00 = *(const bf16x8*)&htile[0][cur][lr*72 +  0 + lg*8];
    bf16x8 h01 = *(const bf16x8*)&htile[0][cur][lr*72 + 32 + lg*8];
    bf16x8 h10 = *(const bf16x8*)&htile[1][cur][lr*72 +  0 + lg*8];
    bf16x8 h11 = *(const bf16x8*)&htile[1][cur][lr*72 + 32 + lg*8];
    f32x4 az0 = (f32x4){0.f,0.f,0.f,0.f}, az1 = az0;
    f32x4 ar0 = az0, ar1 = az0;
    f32x4 aq0 = (f32x4){bhq[0],bhq[1],bhq[2],bhq[3]}, aq1 = aq0;
    az0 = __builtin_amdgcn_mfma_f32_16x16x32_bf16(bf[0][0], h00, az0, 0,0,0);
    az1 = __builtin_amdgcn_mfma_f32_16x16x32_bf16(bf[0][0], h10, az1, 0,0,0);
    ar0 = __builtin_amdgcn_mfma_f32_16x16x32_bf16(bf[1][0], h00, ar0, 0,0,0);
    ar1 = __builtin_amdgcn_mfma_f32_16x16x32_bf16(bf[1][0], h10, ar1, 0,0,0);
    aq0 = __builtin_amdgcn_mfma_f32_16x16x32_bf16(bf[2][0], h00, aq0, 0,0,0);
    aq1 = __builtin_amdgcn_mfma_f32_16x16x32_bf16(bf[2][0], h10, aq1, 0,0,0);
    az0 = __builtin_amdgcn_mfma_f32_16x16x32_bf16(bf[0][1], h01, az0, 0,0,0);
    az1 = __builtin_amdgcn_mfma_f32_16x16x32_bf16(bf[0][1], h11, az1, 0,0,0);
    ar0 = __builtin_amdgcn_mfma_f32_16x16x32_bf16(bf[1][1], h01, ar0, 0,0,0);
    ar1 = __builtin_amdgcn_mfma_f32_16x16x32_bf16(bf[1][1], h11, ar1, 0,0,0);
    aq0 = __builtin_amdgcn_mfma_f32_16x16x32_bf16(bf[2][1], h01, aq0, 0,0,0);
    aq1 = __builtin_amdgcn_mfma_f32_16x16x32_bf16(bf[2][1], h11, aq1, 0,0,0);

    // 3) gates both tiles from prefetched cur regs
    f32x4 hn0, hn1;
    {
      float lz[4]  = { lo16f(c0a.x), lo16f(c0a.z), lo16f(c0b.x), lo16f(c0b.z) };
      float lrr[4] = { hi16f(c0a.x), hi16f(c0a.z), hi16f(c0b.x), hi16f(c0b.z) };
      float lq[4]  = { lo16f(c0a.y), lo16f(c0a.w), lo16f(c0b.y), lo16f(c0b.w) };
      #pragma unroll
      for (int r=0;r<4;r++){
        float z  = fsigmoid(lz[r]  + az0[r]);
        float rr = fsigmoid(lrr[r] + ar0[r]);
        float hh = ftanh(lq[r] + rr*aq0[r]);
        hn0[r] = z*hold0[r] + (1.f-z)*hh;
      }
    }
    {
      float lz[4]  = { lo16f(c1a.x), lo16f(c1a.z), lo16f(c1b.x), lo16f(c1b.z) };
      float lrr[4] = { hi16f(c1a.x), hi16f(c1a.z), hi16f(c1b.x), hi16f(c1b.z) };
      float lq[4]  = { lo16f(c1a.y), lo16f(c1a.w), lo16f(c1b.y), lo16f(c1b.w) };
      #pragma unroll
      for (int r=0;r<4;r++){
        float z  = fsigmoid(lz[r]  + az1[r]);
        float rr = fsigmoid(lrr[r] + ar1[r]);
        float hh = ftanh(lq[r] + rr*aq1[r]);
        hn1[r] = z*hold1[r] + (1.f-z)*hh;
      }
    }
    hold0 = hn0; hold1 = hn1;
    uint2 u0 = make_uint2(pack_bf16(hn0[0], hn0[1]), pack_bf16(hn0[2], hn0[3]));
    uint2 u1 = make_uint2(pack_bf16(hn1[0], hn1[1]), pack_bf16(hn1[2], hn1[3]));
    *(uint2*)&htile[0][cur^1][lr*72 + w*16 + lg*4] = u0;
    *(uint2*)&htile[1][cur^1][lr*72 + w*16 + lg*4] = u1;
    *(uint2*)(seqp0 + (size_t)t*DIM) = u0;
    *(uint2*)(seqp1 + (size_t)t*DIM) = u1;
    __syncthreads();
    cur ^= 1;
    c0a = n0a; c0b = n0b; c1a = n1a; c1b = n1b;
  }
  *(f32x4*)(path_state + (size_t)(p0+lr   )*DIM + w*16 + lg*4) = hold0;
  *(f32x4*)(path_state + (size_t)(p0+16+lr)*DIM + w*16 + lg*4) = hold1;
}

// ---------------- fused link update: 4-wave parallel GRU + next LX ----------------
// block = 4 waves, 16 links. Wave w owns dims w*16+lr: gates nt {w,w+4,w+8}; LX same set.
__global__ __launch_bounds__(256) void link_fused(
    const unsigned short* __restrict__ seq16, const int* __restrict__ ptl,
    const unsigned short* __restrict__ whf,
    const float* __restrict__ lbx, const float* __restrict__ lbh,
    const float* __restrict__ pbx, const float* __restrict__ pbh,
    float* __restrict__ link_state, unsigned short* __restrict__ LXq)
{
  __shared__ float pspart[4][16][64];
  __shared__ float tile[16*68];
  int tid = threadIdx.x, l = tid & 63, w = tid >> 6;
  int lr = l & 15, lg = l >> 4;
  int l0 = blockIdx.x*16;

  // phase 1: partial path_sum gather (10 DEG entries per wave)
  float ps[16];
  #pragma unroll
  for (int i=0;i<16;i++) ps[i]=0.f;
  {
    const int* pe = ptl + (size_t)(l0+lr)*DEG*2 + w*10*2;
    #pragma unroll
    for (int d=0; d<10; d++){
      int pp = pe[2*d], tt = pe[2*d+1];
      const unsigned short* rowp = seq16 + ((size_t)pp*LPATH + (tt-1))*DIM;
      accum8(ps,   *(const uint4*)(rowp + lg*8));
      accum8(ps+8, *(const uint4*)(rowp + 32 + lg*8));
    }
  }
  #pragma unroll
  for (int i=0;i<16;i++) pspart[w][i][l] = ps[i];
  __syncthreads();

  // phase 2: full ps, A-frags, this wave's 3 nt-tiles (z,r,q of dims w*16+lr)
  #pragma unroll
  for (int i=0;i<16;i++)
    ps[i] = pspart[0][i][l] + pspart[1][i][l] + pspart[2][i][l] + pspart[3][i][l];

  bf16x8 phi[2], plo[2], lhi[2], llo[2];
  #pragma unroll
  for (int kc=0;kc<2;kc++){
    split8(ps + kc*8, phi[kc], plo[kc]);
    float hs[8];
    const float* lsr = link_state + (size_t)(l0+lr)*DIM + kc*32 + lg*8;
    *(f32x4*)hs = *(const f32x4*)lsr;
    *(f32x4*)(hs+4) = *(const f32x4*)(lsr+4);
    split8(hs, lhi[kc], llo[kc]);
  }
  f32x4 mxa[3], mha[3];
  #pragma unroll
  for (int j=0;j<3;j++){
    int nt = w + j*4;
    float bxv = lbx[nt*16+lr], bhv = lbh[nt*16+lr];
    mxa[j] = (f32x4){bxv,bxv,bxv,bxv};
    mha[j] = (f32x4){bhv,bhv,bhv,bhv};
    #pragma unroll
    for (int kc=0;kc<2;kc++){
      bf16x8 bwx = *(const bf16x8*)(whf + (size_t)((2*24 + nt*2+kc)*512) + l*8);
      mxa[j] = __builtin_amdgcn_mfma_f32_16x16x32_bf16(phi[kc], bwx, mxa[j], 0,0,0);
      mxa[j] = __builtin_amdgcn_mfma_f32_16x16x32_bf16(plo[kc], bwx, mxa[j], 0,0,0);
      bf16x8 bwh = *(const bf16x8*)(whf + (size_t)((3*24 + nt*2+kc)*512) + l*8);
      mha[j] = __builtin_amdgcn_mfma_f32_16x16x32_bf16(lhi[kc], bwh, mha[j], 0,0,0);
      mha[j] = __builtin_amdgcn_mfma_f32_16x16x32_bf16(llo[kc], bwh, mha[j], 0,0,0);
    }
  }
  __syncthreads();  // all ls reads done before any link_state write

  // gates for dims w*16+lr (z=j0, r=j1, hh=j2)
  #pragma unroll
  for (int r=0;r<4;r++){
    size_t lk = (size_t)(l0 + lg*4 + r)*DIM + w*16 + lr;
    float lsv = link_state[lk];
    float z  = fsigmoid(mxa[0][r] + mha[0][r]);
    float rr = fsigmoid(mxa[1][r] + mha[1][r]);
    float hh = ftanh(mxa[2][r] + rr*mha[2][r]);
    float hn = z*lsv + (1.f-z)*hh;
    link_state[lk] = hn;
    tile[(lg*4+r)*68 + w*16 + lr] = hn;
  }
  __syncthreads();

  // phase 3: next-iter LX, nt {w, w+4, w+8} -> z,r,q of dims w*16+lr; packed uint2 stores
  f32x4 lxa[3];
  #pragma unroll
  for (int j=0;j<3;j++){
    int g = (w + j*4)*16 + lr;
    float b = pbx[g] + (g < 128 ? pbh[g] : 0.f);
    lxa[j] = (f32x4){b,b,b,b};
  }
  #pragma unroll
  for (int kc=0;kc<2;kc++){
    float hs[8];
    #pragma unroll
    for (int i=0;i<8;i++) hs[i] = tile[lr*68 + kc*32 + lg*8 + i];
    bf16x8 thi, tlo; split8(hs, thi, tlo);
    #pragma unroll
    for (int j=0;j<3;j++){
      int nt = w + j*4;
      bf16x8 bw = *(const bf16x8*)(whf + (size_t)((1*24 + nt*2+kc)*512) + l*8);
      lxa[j] = __builtin_amdgcn_mfma_f32_16x16x32_bf16(thi, bw, lxa[j], 0,0,0);
      lxa[j] = __builtin_amdgcn_mfma_f32_16x16x32_bf16(tlo, bw, lxa[j], 0,0,0);
    }
  }
  #pragma unroll
  for (int r=0;r<4;r++){
    int link = l0 + lg*4 + r;
    uint2 u = make_uint2(pack_bf16(lxa[0][r], lxa[1][r]), pack_bf16(lxa[2][r], 0.f));
    *(uint2*)(LXq + (size_t)link*256 + (size_t)(w*16 + lr)*4) = u;
  }
}

// ---------------- readout ----------------
__global__ __launch_bounds__(256) void readout(
    const unsigned short* __restrict__ seq16, const int* __restrict__ ltp,
    const float* __restrict__ cap,
    const float* __restrict__ w1, const float* __restrict__ b1,
    const float* __restrict__ w2, const float* __restrict__ b2,
    const float* __restrict__ w3, const float* __restrict__ b3,
    float* __restrict__ out)
{
  __shared__ unsigned short rows_sh[4][64*72];
  __shared__ float w1s[DIM*32];
  __shared__ float w2s[32*16];
  __shared__ float w3s[16];
  __shared__ float b1s[32], b2s[16];
  int tid = threadIdx.x;
  for (int i=tid;i<DIM*32;i+=256) w1s[i]=w1[i];
  for (int i=tid;i<32*16;i+=256) w2s[i]=w2[i];
  if (tid<16) w3s[tid]=w3[tid];
  if (tid<32) b1s[tid]=b1[tid];
  if (tid<16) b2s[tid]=b2[tid];
  __syncthreads();

  int l = tid & 63, w = tid >> 6;
  size_t wave_r = (size_t)blockIdx.x*256 + (size_t)w*64;
  if (wave_r >= (size_t)N_PATHS*LPATH) return;

  const unsigned short* src = seq16 + wave_r*DIM;
  #pragma unroll
  for (int i=0;i<16;i++){
    int e  = i*64 + l;
    int ri = e >> 4;
    int c4 = e & 15;
    *(uint2*)&rows_sh[w][ri*72 + c4*4] = *(const uint2*)(src + (size_t)e*4);
  }

  size_t row = wave_r + l;
  const unsigned short* myrow = &rows_sh[w][l*72];
  float a[32];
  #pragma unroll
  for (int j=0;j<32;j++) a[j]=b1s[j];
  #pragma unroll
  for (int c=0;c<16;c++){
    uint2 v = *(const uint2*)(myrow + c*4);
    float f0 = __uint_as_float((v.x & 0xFFFFu) << 16);
    float f1 = __uint_as_float(v.x & 0xFFFF0000u);
    float f2 = __uint_as_float((v.y & 0xFFFFu) << 16);
    float f3 = __uint_as_float(v.y & 0xFFFF0000u);
    #pragma unroll
    for (int j=0;j<32;j++) a[j] = fmaf(f0, w1s[(c*4+0)*32+j], a[j]);
    #pragma unroll
    for (int j=0;j<32;j++) a[j] = fmaf(f1, w1s[(c*4+1)*32+j], a[j]);
    #pragma unroll
    for (int j=0;j<32;j++) a[j] = fmaf(f2, w1s[(c*4+2)*32+j], a[j]);
    #pragma unroll
    for (int j=0;j<32;j++) a[j] = fmaf(f3, w1s[(c*4+3)*32+j], a[j]);
  }
  float h2[16];
  #pragma unroll
  for (int j2=0;j2<16;j2++) h2[j2]=b2s[j2];
  #pragma unroll
  for (int j=0;j<32;j++){
    float hv = fmaxf(a[j],0.f);
    #pragma unroll
    for (int j2=0;j2<16;j2++) h2[j2] = fmaf(hv, w2s[j*16+j2], h2[j2]);
  }
  float o = b3[0];
  #pragma unroll
  for (int j2=0;j2<16;j2++) o = fmaf(fmaxf(h2[j2],0.f), w3s[j2], o);
  float sp = (o > 20.f) ? o : log1pf(__expf(o));
  float dly = sp / cap[ltp[row]];
  dly += __shfl_xor(dly, 1);
  dly += __shfl_xor(dly, 2);
  dly += __shfl_xor(dly, 4);
  if ((l & 7) == 0) out[row >> 3] = dly;
}

extern "C" void kernel_launch(void* const* d_in, const int* in_sizes, int n_in,
                              void* d_out, int out_size, void* d_ws, size_t ws_size,
                              hipStream_t stream) {
  const float* ft    = (const float*)d_in[0];
  const float* fpk   = (const float*)d_in[1];
  const float* fps   = (const float*)d_in[2];
  const float* cap   = (const float*)d_in[3];
  const int*   ltp   = (const int*)  d_in[4];
  const int*   ptl   = (const int*)  d_in[5];
  const float* pe_w1 = (const float*)d_in[6];
  const float* pe_b1 = (const float*)d_in[7];
  const float* pe_w2 = (const float*)d_in[8];
  const float* pe_b2 = (const float*)d_in[9];
  const float* le_w1 = (const float*)d_in[10];
  const float* le_b1 = (const float*)d_in[11];
  const float* le_w2 = (const float*)d_in[12];
  const float* le_b2 = (const float*)d_in[13];
  const float* pg_wx = (const float*)d_in[14];
  const float* pg_wh = (const float*)d_in[15];
  const float* pg_bx = (const float*)d_in[16];
  const float* pg_bh = (const float*)d_in[17];
  const float* lg_wx = (const float*)d_in[18];
  const float* lg_wh = (const float*)d_in[19];
  const float* lg_bx = (const float*)d_in[20];
  const float* lg_bh = (const float*)d_in[21];
  const float* ro_w1 = (const float*)d_in[22];
  const float* ro_b1 = (const float*)d_in[23];
  const float* ro_w2 = (const float*)d_in[24];
  const float* ro_b2 = (const float*)d_in[25];
  const float* ro_w3 = (const float*)d_in[26];
  const float* ro_b3 = (const float*)d_in[27];
  float* out = (float*)d_out;

  float* path_state = (float*)d_ws;
  float* link_state = path_state + (size_t)N_PATHS*DIM;
  unsigned short* LXq   = (unsigned short*)(link_state + (size_t)N_LINKS*DIM);  // 10000*256
  unsigned short* seq16 = LXq + (size_t)N_LINKS*256;
  unsigned short* whf   = seq16 + (size_t)N_PATHS*LPATH*DIM;

  path_embed<<<N_PATHS/4, 256, 0, stream>>>(ft, fpk, fps, pe_w1, pe_b1, pe_w2, pe_b2, path_state);
  link_embed<<<N_LINKS/4, 256, 0, stream>>>(ft, cap, ptl, le_w1, le_b1, le_w2, le_b2, link_state);
  pack_frags<<<192, 256, 0, stream>>>(pg_wh, pg_wx, lg_wx, lg_wh, whf);
  compute_lx<<<N_LINKS/4, 192, 0, stream>>>(link_state, pg_wx, pg_bx, pg_bh, LXq);
  for (int it=0; it<ITERS; ++it){
    path_scan_mfma<<<(N_PATHS+31)/32, 256, 0, stream>>>(LXq, ltp, whf, pg_bh, path_state, seq16);
    if (it < ITERS-1)
      link_fused<<<N_LINKS/16, 256, 0, stream>>>(seq16, ptl, whf,
          lg_bx, lg_bh, pg_bx, pg_bh, link_state, LXq);
  }
  readout<<<(N_PATHS*LPATH + 255)/256, 256, 0, stream>>>(seq16, ltp, cap,
      ro_w1, ro_b1, ro_w2, ro_b2, ro_w3, ro_b3, out);
}

// Round 10
// 633.782 us; speedup vs baseline: 1.1013x; 1.1013x over previous
//
#include <hip/hip_runtime.h>
#include <math.h>

#define N_PATHS 50000
#define N_LINKS 10000
#define LPATH   8
#define DEG     40
#define DIM     64
#define G3      192
#define ITERS   8

typedef float f32x4  __attribute__((ext_vector_type(4)));
typedef short bf16x8 __attribute__((ext_vector_type(8)));

__device__ __forceinline__ float fsigmoid(float x){ return 1.0f/(1.0f + __expf(-x)); }
__device__ __forceinline__ float ftanh(float x){ return 1.0f - 2.0f/(__expf(2.0f*x) + 1.0f); }
__device__ __forceinline__ unsigned short bf16_rne(float v){
  unsigned u = __float_as_uint(v);
  return (unsigned short)((u + 0x7FFFu + ((u>>16)&1u)) >> 16);
}
// packed bf16 pair: lo16 = bf16(a), hi16 = bf16(b). RNE, single HW op on gfx950.
__device__ __forceinline__ unsigned pack_bf16(float a, float b){
  unsigned r;
  asm("v_cvt_pk_bf16_f32 %0, %1, %2" : "=v"(r) : "v"(a), "v"(b));
  return r;
}
__device__ __forceinline__ float lo16f(unsigned v){ return __uint_as_float(v << 16); }
__device__ __forceinline__ float hi16f(unsigned v){ return __uint_as_float(v & 0xFFFF0000u); }
// split 8 fp32 into bf16 hi + bf16 residual
__device__ __forceinline__ void split8(const float* s, bf16x8& hi, bf16x8& lo){
  #pragma unroll
  for (int e=0;e<8;e++){
    unsigned short hb = bf16_rne(s[e]);
    float lof = s[e] - __uint_as_float(((unsigned)hb)<<16);
    hi[e] = (short)hb; lo[e] = (short)bf16_rne(lof);
  }
}
__device__ __forceinline__ void accum8(float* a, uint4 v){
  unsigned x[4] = {v.x, v.y, v.z, v.w};
  #pragma unroll
  for (int q=0;q<4;q++){
    a[2*q]   += __uint_as_float((x[q]&0xFFFFu)<<16);
    a[2*q+1] += __uint_as_float(x[q]&0xFFFF0000u);
  }
}

// ---------------- path embedding ----------------
__global__ __launch_bounds__(256) void path_embed(
    const float* __restrict__ ft, const float* __restrict__ fp, const float* __restrict__ fps,
    const float* __restrict__ w1, const float* __restrict__ b1,
    const float* __restrict__ w2, const float* __restrict__ b2,
    float* __restrict__ path_state)
{
  __shared__ float h1[4][DIM];
  int j  = threadIdx.x & 63;
  int pl = threadIdx.x >> 6;
  int p  = blockIdx.x*4 + pl;
  float x0 = ft[p]*1e-4f, x1 = fp[p]*1e-3f, x2 = fps[p]*1e-3f;
  float h = b1[j] + x0*w1[0*DIM+j] + x1*w1[1*DIM+j] + x2*w1[2*DIM+j];
  h1[pl][j] = fmaxf(h, 0.f);
  __syncthreads();
  float acc = b2[j];
  #pragma unroll 8
  for (int k=0;k<DIM;k++) acc = fmaf(h1[pl][k], w2[k*DIM+j], acc);
  path_state[p*DIM+j] = fmaxf(acc, 0.f);
}

// ---------------- link embedding ----------------
__global__ __launch_bounds__(256) void link_embed(
    const float* __restrict__ ft, const float* __restrict__ cap, const int* __restrict__ ptl,
    const float* __restrict__ w1, const float* __restrict__ b1,
    const float* __restrict__ w2, const float* __restrict__ b2,
    float* __restrict__ link_state)
{
  __shared__ float h1[4][DIM];
  int j  = threadIdx.x & 63;
  int wl = threadIdx.x >> 6;
  int l  = blockIdx.x*4 + wl;
  float s = 0.f;
  if (j < DEG) s = ft[ptl[(l*DEG + j)*2 + 0]];
  #pragma unroll
  for (int off=32; off; off>>=1) s += __shfl_down(s, off);
  float load = __shfl(s, 0) / (cap[l]*1e9f);
  float x0 = cap[l]*1e-5f;
  float h = b1[j] + x0*w1[0*DIM+j] + load*w1[1*DIM+j];
  h1[wl][j] = fmaxf(h, 0.f);
  __syncthreads();
  float acc = b2[j];
  #pragma unroll 8
  for (int k=0;k<DIM;k++) acc = fmaf(h1[wl][k], w2[k*DIM+j], acc);
  link_state[l*DIM+j] = fmaxf(acc, 0.f);
}

// ---------------- pack 4 weight mats into bf16 MFMA fragments ----------------
// m: 0=pg_wh, 1=pg_wx, 2=lg_wx, 3=lg_wh. frag f=nt*2+kc.
// elem i of lane l = w[kc*32+(l>>4)*8+i][nt*16+(l&15)]  (A- and B-operand maps coincide)
__global__ __launch_bounds__(256) void pack_frags(
    const float* __restrict__ pg_wh, const float* __restrict__ pg_wx,
    const float* __restrict__ lg_wx, const float* __restrict__ lg_wh,
    unsigned short* __restrict__ whf)
{
  int tid = blockIdx.x*256 + threadIdx.x;
  if (tid >= 4*24*512) return;
  int i = tid & 7, l = (tid>>3)&63, f = (tid>>9)%24, m = tid/(24*512);
  int nt = f>>1, kc = f&1;
  int k = kc*32 + (l>>4)*8 + i;
  int n = nt*16 + (l&15);
  const float* src = (m==0)?pg_wh : (m==1)?pg_wx : (m==2)?lg_wx : lg_wh;
  whf[tid] = bf16_rne(src[k*G3 + n]);
}

// ---------------- initial LX, packed bf16, NO PAD: 384 B/link (fits per-XCD 4MB L2) ----------------
// LXq[link][dim][{z,r,q}]: pos = dim*3 + comp, row stride 192 ushorts
__global__ __launch_bounds__(192) void compute_lx(
    const float* __restrict__ link_state, const float* __restrict__ wx,
    const float* __restrict__ bx, const float* __restrict__ bh,
    unsigned short* __restrict__ LXq)
{
  __shared__ float ls[4][DIM];
  int g  = threadIdx.x;
  int l0 = blockIdx.x*4;
  if (g < DIM){
    #pragma unroll
    for (int li=0; li<4; li++) ls[li][g] = link_state[(l0+li)*DIM+g];
  }
  __syncthreads();
  float b = bx[g] + (g < 128 ? bh[g] : 0.f);
  float a0=b, a1=b, a2=b, a3=b;
  #pragma unroll 8
  for (int k=0;k<DIM;k++){
    float w = wx[k*G3+g];
    a0 = fmaf(ls[0][k], w, a0);
    a1 = fmaf(ls[1][k], w, a1);
    a2 = fmaf(ls[2][k], w, a2);
    a3 = fmaf(ls[3][k], w, a3);
  }
  int comp = g >> 6, dim = g & 63;
  int pos = dim*3 + comp;
  LXq[(size_t)(l0+0)*G3+pos]=bf16_rne(a0);
  LXq[(size_t)(l0+1)*G3+pos]=bf16_rne(a1);
  LXq[(size_t)(l0+2)*G3+pos]=bf16_rne(a2);
  LXq[(size_t)(l0+3)*G3+pos]=bf16_rne(a3);
}

// ---------------- MFMA 8-step GRU scan: transposed-D n-split + LX prefetch ----------------
// block = 4 waves, ONE 16-path tile. Wave w owns dims w*16..+15.
// mfma(W_frag, h_frag, acc): lane holds path lr, dims w*16+lg*4+reg. 1 barrier/step.
__global__ __launch_bounds__(256) void path_scan_mfma(
    const unsigned short* __restrict__ LXq, const int* __restrict__ ltp,
    const unsigned short* __restrict__ whf, const float* __restrict__ bh,
    float* __restrict__ path_state, unsigned short* __restrict__ seq16)
{
  __shared__ __align__(16) unsigned short htile[2][16*72];  // [buf][path][dim], pitch 72
  __shared__ int ltps[128];
  int tid = threadIdx.x, l = tid & 63, w = tid >> 6;
  int lg = l >> 4, lr = l & 15;
  int p0 = blockIdx.x*16;                 // 50000/16 = 3125 exact

  // this wave's 6 W-fragments of pg_wh (nt = w, w+4, w+8 -> z, r, q)
  bf16x8 bf[3][2];
  #pragma unroll
  for (int j=0;j<3;j++){
    int nt = w + j*4;
    bf[j][0] = *(const bf16x8*)(whf + (size_t)(nt*2+0)*512 + l*8);
    bf[j][1] = *(const bf16x8*)(whf + (size_t)(nt*2+1)*512 + l*8);
  }
  float bhq[4];
  #pragma unroll
  for (int r=0;r<4;r++) bhq[r] = bh[128 + w*16 + lg*4 + r];

  if (tid < 128) ltps[tid] = ltp[(size_t)p0*LPATH + tid];

  // stage h -> htile[0] bf16 (coalesced float4 reads, packed 8B LDS writes)
  {
    int pi = tid >> 4, c4 = (tid & 15)*4;
    float4 v = *(const float4*)(path_state + (size_t)(p0+pi)*DIM + c4);
    uint2 u = make_uint2(pack_bf16(v.x, v.y), pack_bf16(v.z, v.w));
    *(uint2*)&htile[0][pi*72 + c4] = u;
  }
  // fp32 h_old: path lr, dims w*16+lg*4..+4 (contiguous float4)
  f32x4 hold = *(const f32x4*)(path_state + (size_t)(p0+lr)*DIM + w*16 + lg*4);

  __syncthreads();

  unsigned short* seqp = seq16 + ((size_t)(p0+lr)*LPATH)*DIM + w*16 + lg*4;
  const size_t dimoff = (size_t)(w*16 + lg*4)*3;   // ushort offset into 384B row
  int cur = 0;

  // prefetch t=0 LX: 3 x 8B-aligned uint2 = dims lg*4..+4, comps {z,r,q}
  uint2 c0, c1, c2;
  {
    const unsigned short* x = LXq + (size_t)ltps[lr*LPATH]*G3 + dimoff;
    c0 = *(const uint2*)x; c1 = *(const uint2*)(x+4); c2 = *(const uint2*)(x+8);
  }

  for (int t=0; t<LPATH; t++){
    // 1) issue NEXT step's LX gather (full step to land; L2-resident 3.84MB array)
    int tn = (t < LPATH-1) ? t+1 : t;
    const unsigned short* xn = LXq + (size_t)ltps[lr*LPATH + tn]*G3 + dimoff;
    uint2 n0 = *(const uint2*)xn, n1 = *(const uint2*)(xn+4), n2 = *(const uint2*)(xn+8);

    // 2) h fragments + 6 MFMAs (depend only on LDS)
    bf16x8 h0 = *(const bf16x8*)&htile[cur][lr*72 +  0 + lg*8];
    bf16x8 h1 = *(const bf16x8*)&htile[cur][lr*72 + 32 + lg*8];
    f32x4 accz = (f32x4){0.f,0.f,0.f,0.f};
    f32x4 accr = (f32x4){0.f,0.f,0.f,0.f};
    f32x4 accq = (f32x4){bhq[0],bhq[1],bhq[2],bhq[3]};
    accz = __builtin_amdgcn_mfma_f32_16x16x32_bf16(bf[0][0], h0, accz, 0,0,0);
    accr = __builtin_amdgcn_mfma_f32_16x16x32_bf16(bf[1][0], h0, accr, 0,0,0);
    accq = __builtin_amdgcn_mfma_f32_16x16x32_bf16(bf[2][0], h0, accq, 0,0,0);
    accz = __builtin_amdgcn_mfma_f32_16x16x32_bf16(bf[0][1], h1, accz, 0,0,0);
    accr = __builtin_amdgcn_mfma_f32_16x16x32_bf16(bf[1][1], h1, accr, 0,0,0);
    accq = __builtin_amdgcn_mfma_f32_16x16x32_bf16(bf[2][1], h1, accq, 0,0,0);

    // 3) gates consume CURRENT prefetched LX regs
    // ushort seq: z0,r0,q0,z1 | r1,q1,z2,r2 | q2,z3,r3,q3
    float lz[4]  = { lo16f(c0.x), hi16f(c0.y), lo16f(c1.y), hi16f(c2.x) };
    float lrr[4] = { hi16f(c0.x), lo16f(c1.x), hi16f(c1.y), lo16f(c2.y) };
    float lq[4]  = { lo16f(c0.y), hi16f(c1.x), lo16f(c2.x), hi16f(c2.y) };
    f32x4 hn;
    #pragma unroll
    for (int r=0;r<4;r++){
      float z  = fsigmoid(lz[r]  + accz[r]);
      float rr = fsigmoid(lrr[r] + accr[r]);
      float hh = ftanh(lq[r] + rr*accq[r]);
      hn[r] = z*hold[r] + (1.f-z)*hh;
    }
    hold = hn;
    uint2 u = make_uint2(pack_bf16(hn[0], hn[1]), pack_bf16(hn[2], hn[3]));
    *(uint2*)&htile[cur^1][lr*72 + w*16 + lg*4] = u;   // next-step h (bf16)
    *(uint2*)(seqp + (size_t)t*DIM) = u;               // direct reg->global seq store
    __syncthreads();
    cur ^= 1;
    c0 = n0; c1 = n1; c2 = n2;
  }
  *(f32x4*)(path_state + (size_t)(p0+lr)*DIM + w*16 + lg*4) = hold;
}

// ---------------- fused link update: 4-wave parallel GRU + next LX ----------------
// block = 4 waves, 16 links. Wave w owns dims w*16+lr: gates nt {w,w+4,w+8}; LX same set.
__global__ __launch_bounds__(256) void link_fused(
    const unsigned short* __restrict__ seq16, const int* __restrict__ ptl,
    const unsigned short* __restrict__ whf,
    const float* __restrict__ lbx, const float* __restrict__ lbh,
    const float* __restrict__ pbx, const float* __restrict__ pbh,
    float* __restrict__ link_state, unsigned short* __restrict__ LXq)
{
  __shared__ float pspart[4][16][64];
  __shared__ float tile[16*68];
  int tid = threadIdx.x, l = tid & 63, w = tid >> 6;
  int lr = l & 15, lg = l >> 4;
  int l0 = blockIdx.x*16;

  // phase 1: partial path_sum gather (10 DEG entries per wave)
  float ps[16];
  #pragma unroll
  for (int i=0;i<16;i++) ps[i]=0.f;
  {
    const int* pe = ptl + (size_t)(l0+lr)*DEG*2 + w*10*2;
    #pragma unroll
    for (int d=0; d<10; d++){
      int pp = pe[2*d], tt = pe[2*d+1];
      const unsigned short* rowp = seq16 + ((size_t)pp*LPATH + (tt-1))*DIM;
      accum8(ps,   *(const uint4*)(rowp + lg*8));
      accum8(ps+8, *(const uint4*)(rowp + 32 + lg*8));
    }
  }
  #pragma unroll
  for (int i=0;i<16;i++) pspart[w][i][l] = ps[i];
  __syncthreads();

  // phase 2: full ps, A-frags, this wave's 3 nt-tiles (z,r,q of dims w*16+lr)
  #pragma unroll
  for (int i=0;i<16;i++)
    ps[i] = pspart[0][i][l] + pspart[1][i][l] + pspart[2][i][l] + pspart[3][i][l];

  bf16x8 phi[2], plo[2], lhi[2], llo[2];
  #pragma unroll
  for (int kc=0;kc<2;kc++){
    split8(ps + kc*8, phi[kc], plo[kc]);
    float hs[8];
    const float* lsr = link_state + (size_t)(l0+lr)*DIM + kc*32 + lg*8;
    *(f32x4*)hs = *(const f32x4*)lsr;
    *(f32x4*)(hs+4) = *(const f32x4*)(lsr+4);
    split8(hs, lhi[kc], llo[kc]);
  }
  f32x4 mxa[3], mha[3];
  #pragma unroll
  for (int j=0;j<3;j++){
    int nt = w + j*4;
    float bxv = lbx[nt*16+lr], bhv = lbh[nt*16+lr];
    mxa[j] = (f32x4){bxv,bxv,bxv,bxv};
    mha[j] = (f32x4){bhv,bhv,bhv,bhv};
    #pragma unroll
    for (int kc=0;kc<2;kc++){
      bf16x8 bwx = *(const bf16x8*)(whf + (size_t)((2*24 + nt*2+kc)*512) + l*8);
      mxa[j] = __builtin_amdgcn_mfma_f32_16x16x32_bf16(phi[kc], bwx, mxa[j], 0,0,0);
      mxa[j] = __builtin_amdgcn_mfma_f32_16x16x32_bf16(plo[kc], bwx, mxa[j], 0,0,0);
      bf16x8 bwh = *(const bf16x8*)(whf + (size_t)((3*24 + nt*2+kc)*512) + l*8);
      mha[j] = __builtin_amdgcn_mfma_f32_16x16x32_bf16(lhi[kc], bwh, mha[j], 0,0,0);
      mha[j] = __builtin_amdgcn_mfma_f32_16x16x32_bf16(llo[kc], bwh, mha[j], 0,0,0);
    }
  }
  __syncthreads();  // all ls reads done before any link_state write

  // gates for dims w*16+lr (z=j0, r=j1, hh=j2)
  #pragma unroll
  for (int r=0;r<4;r++){
    size_t lk = (size_t)(l0 + lg*4 + r)*DIM + w*16 + lr;
    float lsv = link_state[lk];
    float z  = fsigmoid(mxa[0][r] + mha[0][r]);
    float rr = fsigmoid(mxa[1][r] + mha[1][r]);
    float hh = ftanh(mxa[2][r] + rr*mha[2][r]);
    float hn = z*lsv + (1.f-z)*hh;
    link_state[lk] = hn;
    tile[(lg*4+r)*68 + w*16 + lr] = hn;
  }
  __syncthreads();

  // phase 3: next-iter LX, nt {w, w+4, w+8} -> z,r,q of dims w*16+lr; packed 384B rows
  f32x4 lxa[3];
  #pragma unroll
  for (int j=0;j<3;j++){
    int g = (w + j*4)*16 + lr;
    float b = pbx[g] + (g < 128 ? pbh[g] : 0.f);
    lxa[j] = (f32x4){b,b,b,b};
  }
  #pragma unroll
  for (int kc=0;kc<2;kc++){
    float hs[8];
    #pragma unroll
    for (int i=0;i<8;i++) hs[i] = tile[lr*68 + kc*32 + lg*8 + i];
    bf16x8 thi, tlo; split8(hs, thi, tlo);
    #pragma unroll
    for (int j=0;j<3;j++){
      int nt = w + j*4;
      bf16x8 bw = *(const bf16x8*)(whf + (size_t)((1*24 + nt*2+kc)*512) + l*8);
      lxa[j] = __builtin_amdgcn_mfma_f32_16x16x32_bf16(thi, bw, lxa[j], 0,0,0);
      lxa[j] = __builtin_amdgcn_mfma_f32_16x16x32_bf16(tlo, bw, lxa[j], 0,0,0);
    }
  }
  #pragma unroll
  for (int r=0;r<4;r++){
    int link = l0 + lg*4 + r;
    size_t base = (size_t)link*G3 + (size_t)(w*16 + lr)*3;
    LXq[base+0] = bf16_rne(lxa[0][r]);
    LXq[base+1] = bf16_rne(lxa[1][r]);
    LXq[base+2] = bf16_rne(lxa[2][r]);
  }
}

// ---------------- readout ----------------
__global__ __launch_bounds__(256) void readout(
    const unsigned short* __restrict__ seq16, const int* __restrict__ ltp,
    const float* __restrict__ cap,
    const float* __restrict__ w1, const float* __restrict__ b1,
    const float* __restrict__ w2, const float* __restrict__ b2,
    const float* __restrict__ w3, const float* __restrict__ b3,
    float* __restrict__ out)
{
  __shared__ unsigned short rows_sh[4][64*72];
  __shared__ float w1s[DIM*32];
  __shared__ float w2s[32*16];
  __shared__ float w3s[16];
  __shared__ float b1s[32], b2s[16];
  int tid = threadIdx.x;
  for (int i=tid;i<DIM*32;i+=256) w1s[i]=w1[i];
  for (int i=tid;i<32*16;i+=256) w2s[i]=w2[i];
  if (tid<16) w3s[tid]=w3[tid];
  if (tid<32) b1s[tid]=b1[tid];
  if (tid<16) b2s[tid]=b2[tid];
  __syncthreads();

  int l = tid & 63, w = tid >> 6;
  size_t wave_r = (size_t)blockIdx.x*256 + (size_t)w*64;
  if (wave_r >= (size_t)N_PATHS*LPATH) return;

  const unsigned short* src = seq16 + wave_r*DIM;
  #pragma unroll
  for (int i=0;i<16;i++){
    int e  = i*64 + l;
    int ri = e >> 4;
    int c4 = e & 15;
    *(uint2*)&rows_sh[w][ri*72 + c4*4] = *(const uint2*)(src + (size_t)e*4);
  }

  size_t row = wave_r + l;
  const unsigned short* myrow = &rows_sh[w][l*72];
  float a[32];
  #pragma unroll
  for (int j=0;j<32;j++) a[j]=b1s[j];
  #pragma unroll
  for (int c=0;c<16;c++){
    uint2 v = *(const uint2*)(myrow + c*4);
    float f0 = __uint_as_float((v.x & 0xFFFFu) << 16);
    float f1 = __uint_as_float(v.x & 0xFFFF0000u);
    float f2 = __uint_as_float((v.y & 0xFFFFu) << 16);
    float f3 = __uint_as_float(v.y & 0xFFFF0000u);
    #pragma unroll
    for (int j=0;j<32;j++) a[j] = fmaf(f0, w1s[(c*4+0)*32+j], a[j]);
    #pragma unroll
    for (int j=0;j<32;j++) a[j] = fmaf(f1, w1s[(c*4+1)*32+j], a[j]);
    #pragma unroll
    for (int j=0;j<32;j++) a[j] = fmaf(f2, w1s[(c*4+2)*32+j], a[j]);
    #pragma unroll
    for (int j=0;j<32;j++) a[j] = fmaf(f3, w1s[(c*4+3)*32+j], a[j]);
  }
  float h2[16];
  #pragma unroll
  for (int j2=0;j2<16;j2++) h2[j2]=b2s[j2];
  #pragma unroll
  for (int j=0;j<32;j++){
    float hv = fmaxf(a[j],0.f);
    #pragma unroll
    for (int j2=0;j2<16;j2++) h2[j2] = fmaf(hv, w2s[j*16+j2], h2[j2]);
  }
  float o = b3[0];
  #pragma unroll
  for (int j2=0;j2<16;j2++) o = fmaf(fmaxf(h2[j2],0.f), w3s[j2], o);
  float sp = (o > 20.f) ? o : log1pf(__expf(o));
  float dly = sp / cap[ltp[row]];
  dly += __shfl_xor(dly, 1);
  dly += __shfl_xor(dly, 2);
  dly += __shfl_xor(dly, 4);
  if ((l & 7) == 0) out[row >> 3] = dly;
}

extern "C" void kernel_launch(void* const* d_in, const int* in_sizes, int n_in,
                              void* d_out, int out_size, void* d_ws, size_t ws_size,
                              hipStream_t stream) {
  const float* ft    = (const float*)d_in[0];
  const float* fpk   = (const float*)d_in[1];
  const float* fps   = (const float*)d_in[2];
  const float* cap   = (const float*)d_in[3];
  const int*   ltp   = (const int*)  d_in[4];
  const int*   ptl   = (const int*)  d_in[5];
  const float* pe_w1 = (const float*)d_in[6];
  const float* pe_b1 = (const float*)d_in[7];
  const float* pe_w2 = (const float*)d_in[8];
  const float* pe_b2 = (const float*)d_in[9];
  const float* le_w1 = (const float*)d_in[10];
  const float* le_b1 = (const float*)d_in[11];
  const float* le_w2 = (const float*)d_in[12];
  const float* le_b2 = (const float*)d_in[13];
  const float* pg_wx = (const float*)d_in[14];
  const float* pg_wh = (const float*)d_in[15];
  const float* pg_bx = (const float*)d_in[16];
  const float* pg_bh = (const float*)d_in[17];
  const float* lg_wx = (const float*)d_in[18];
  const float* lg_wh = (const float*)d_in[19];
  const float* lg_bx = (const float*)d_in[20];
  const float* lg_bh = (const float*)d_in[21];
  const float* ro_w1 = (const float*)d_in[22];
  const float* ro_b1 = (const float*)d_in[23];
  const float* ro_w2 = (const float*)d_in[24];
  const float* ro_b2 = (const float*)d_in[25];
  const float* ro_w3 = (const float*)d_in[26];
  const float* ro_b3 = (const float*)d_in[27];
  float* out = (float*)d_out;

  float* path_state = (float*)d_ws;
  float* link_state = path_state + (size_t)N_PATHS*DIM;
  unsigned short* LXq   = (unsigned short*)(link_state + (size_t)N_LINKS*DIM);  // 10000*192 (384B rows)
  unsigned short* seq16 = LXq + (size_t)N_LINKS*G3;
  unsigned short* whf   = seq16 + (size_t)N_PATHS*LPATH*DIM;

  path_embed<<<N_PATHS/4, 256, 0, stream>>>(ft, fpk, fps, pe_w1, pe_b1, pe_w2, pe_b2, path_state);
  link_embed<<<N_LINKS/4, 256, 0, stream>>>(ft, cap, ptl, le_w1, le_b1, le_w2, le_b2, link_state);
  pack_frags<<<192, 256, 0, stream>>>(pg_wh, pg_wx, lg_wx, lg_wh, whf);
  compute_lx<<<N_LINKS/4, 192, 0, stream>>>(link_state, pg_wx, pg_bx, pg_bh, LXq);
  for (int it=0; it<ITERS; ++it){
    path_scan_mfma<<<N_PATHS/16, 256, 0, stream>>>(LXq, ltp, whf, pg_bh, path_state, seq16);
    if (it < ITERS-1)
      link_fused<<<N_LINKS/16, 256, 0, stream>>>(seq16, ptl, whf,
          lg_bx, lg_bh, pg_bx, pg_bh, link_state, LXq);
  }
  readout<<<(N_PATHS*LPATH + 255)/256, 256, 0, stream>>>(seq16, ltp, cap,
      ro_w1, ro_b1, ro_w2, ro_b2, ro_w3, ro_b3, out);
}